// Round 9
// baseline (216.579 us; speedup 1.0000x reference)
//
#include <hip/hip_runtime.h>
#include <math.h>

typedef __attribute__((ext_vector_type(8))) short bf16x8;
typedef __attribute__((ext_vector_type(4))) float f32x4;

__device__ __forceinline__ ushort f2bf(float f) {
  union { float f; unsigned u; } v; v.f = f;
  return (ushort)((v.u + 0x8000u) >> 16);
}

// async global->LDS, 16B per lane. lds base wave-uniform; lane i lands at base + i*16B.
__device__ __forceinline__ void g2l16(const void* g, void* l) {
  __builtin_amdgcn_global_load_lds((const __attribute__((address_space(1))) unsigned*)g,
                                   (__attribute__((address_space(3))) unsigned*)l, 16, 0, 0);
}

// ---------------- merged cast + zero kernel ----------------
// idx [0,1M): x -> xbf.  [1M,2M): weights -> wcat (Wq scaled).  [2M,3M): zero O32.
__global__ __launch_bounds__(256) void cast_all(const float* __restrict__ x,
                                                const float* __restrict__ Wq,
                                                const float* __restrict__ Wk,
                                                const float* __restrict__ Wv,
                                                const float* __restrict__ Wo,
                                                ushort* __restrict__ xbf,
                                                ushort* __restrict__ wcat,
                                                float4* __restrict__ O32) {
  int i = blockIdx.x * 256 + threadIdx.x;
  if (i < 1048576) {
    float4 v = ((const float4*)x)[i];
    ushort4 u; u.x = f2bf(v.x); u.y = f2bf(v.y); u.z = f2bf(v.z); u.w = f2bf(v.w);
    ((ushort4*)xbf)[i] = u;
  } else if (i < 2097152) {
    int j = i - 1048576;
    int sel = j >> 18;
    const float* src = (sel == 0) ? Wq : (sel == 1) ? Wk : (sel == 2) ? Wv : Wo;
    float scale = (sel == 0) ? 0.125f * 1.44269504088896f : 1.0f;  // fold D^-0.5 * log2e
    float4 v = ((const float4*)src)[j & 0x3FFFF];
    ushort4 u;
    u.x = f2bf(v.x * scale); u.y = f2bf(v.y * scale);
    u.z = f2bf(v.z * scale); u.w = f2bf(v.w * scale);
    ((ushort4*)wcat)[j] = u;
  } else {
    O32[i - 2097152] = float4{0.f, 0.f, 0.f, 0.f};
  }
}

// ---------------- QKV GEMM: C = A @ B^T, 128x128, BK=32, dbuf ----------------
// Q/K planes stored token-major; V blocks write Vt[bh][d][t] directly via an LDS
// transpose that reuses the (dead) staging buffers in the epilogue.
__global__ __launch_bounds__(256) void gemm_qkv(const ushort* __restrict__ A,
                                                const ushort* __restrict__ B,
                                                ushort* __restrict__ C3,
                                                ushort* __restrict__ Vt) {
  const int K = 1024;
  // union: staging (2x2x4096 ushorts = 32 KB) vs epilogue transpose T[128][136] (34.8 KB)
  __shared__ __align__(16) ushort smem[17408];
  ushort* As = smem;           // [2][128*32]
  ushort* Bs = smem + 8192;    // [2][128*32]
  const int m0 = blockIdx.y * 128, n0 = blockIdx.x * 128;
  const int tid = threadIdx.x, lane = tid & 63, wid = tid >> 6;
  const int quad = lane >> 4, lc = lane & 15;
  const int lrow = lane >> 2, lcol = (lane & 3) * 8;
  const int wm = (wid >> 1) * 64, wn = (wid & 1) * 64;

  f32x4 acc[4][4] = {};

  auto stage = [&](int k0, int nb) {
    const ushort* Ag = A + (size_t)(m0 + wid * 32 + lrow) * K + k0 + lcol;
    g2l16(Ag, &As[nb * 4096 + wid * 1024]);
    g2l16(Ag + (size_t)16 * K, &As[nb * 4096 + wid * 1024 + 512]);
    const ushort* Bg = B + (size_t)(n0 + wid * 32 + lrow) * K + k0 + lcol;
    g2l16(Bg, &Bs[nb * 4096 + wid * 1024]);
    g2l16(Bg + (size_t)16 * K, &Bs[nb * 4096 + wid * 1024 + 512]);
  };

  stage(0, 0);
  for (int k0 = 0; k0 < K; k0 += 32) {
    const int nb = (k0 >> 5) & 1;
    __syncthreads();
    if (k0 + 32 < K) stage(k0 + 32, nb ^ 1);

    bf16x8 af[4], bfr[4];
#pragma unroll
    for (int t = 0; t < 4; t++)
      af[t] = *(const bf16x8*)&As[nb * 4096 + (wm + t * 16 + lc) * 32 + quad * 8];
#pragma unroll
    for (int t = 0; t < 4; t++)
      bfr[t] = *(const bf16x8*)&Bs[nb * 4096 + (wn + t * 16 + lc) * 32 + quad * 8];
#pragma unroll
    for (int mt = 0; mt < 4; mt++)
#pragma unroll
      for (int nt = 0; nt < 4; nt++)
        acc[mt][nt] = __builtin_amdgcn_mfma_f32_16x16x32_bf16(af[mt], bfr[nt], acc[mt][nt], 0, 0, 0);
  }

  const int sel = n0 >> 10;   // 0=Q, 1=K, 2=V (block-uniform)
  if (sel < 2) {
#pragma unroll
    for (int mt = 0; mt < 4; mt++) {
#pragma unroll
      for (int r = 0; r < 4; r++) {
        int row = m0 + wm + mt * 16 + quad * 4 + r;
#pragma unroll
        for (int nt = 0; nt < 4; nt++) {
          int col = n0 + wn + nt * 16 + lc;
          size_t dst = ((size_t)sel << 22) + (size_t)row * 1024 + (col & 1023);
          C3[dst] = f2bf(acc[mt][nt][r]);
        }
      }
    }
  } else {
    // transpose through LDS: T[d_local 128][token_local 128], pitch 136 (conflict-free)
    __syncthreads();   // staging buffers dead (last frags already consumed by MFMA waits)
#pragma unroll
    for (int mt = 0; mt < 4; mt++)
#pragma unroll
      for (int r = 0; r < 4; r++) {
        int tl = wm + mt * 16 + quad * 4 + r;
#pragma unroll
        for (int nt = 0; nt < 4; nt++)
          smem[(wn + nt * 16 + lc) * 136 + tl] = f2bf(acc[mt][nt][r]);
      }
    __syncthreads();
    const int hd0 = n0 - 2048, b = m0 >> 11, t_base = m0 & 2047;
#pragma unroll
    for (int i = 0; i < 8; i++) {
      int idx = i * 256 + tid;
      int dl = idx >> 4, tc = (idx & 15) * 8;
      uint4 v = *(const uint4*)&smem[dl * 136 + tc];
      int hd = hd0 + dl;
      *(uint4*)(Vt + (size_t)(b * 16 + (hd >> 6)) * 131072 +
                (size_t)(hd & 63) * 2048 + t_base + tc) = v;
    }
  }
}

// ---------------- proj GEMM: out[4096][1024] = attn_out @ Wo^T + bo, BK=64 ----------------
__global__ __launch_bounds__(256) void gemm_proj(const ushort* __restrict__ A,
                                                 const ushort* __restrict__ B,
                                                 float* __restrict__ C,
                                                 const float* __restrict__ bias) {
  const int K = 1024;
  __shared__ __align__(16) ushort As[2][2][128 * 32];  // [buf][k-half][row][32]
  __shared__ __align__(16) ushort Bs[2][2][64 * 32];
  const int m0 = blockIdx.y * 128, n0 = blockIdx.x * 64;
  const int tid = threadIdx.x, lane = tid & 63, wid = tid >> 6;
  const int quad = lane >> 4, lc = lane & 15;
  const int lrow = lane >> 2, lcol = (lane & 3) * 8;
  const int wm = (wid >> 1) * 64, wn = (wid & 1) * 32;

  f32x4 acc[4][2] = {};

  auto stage = [&](int k0, int nb) {
    const ushort* Ag = A + (size_t)(m0 + wid * 32 + lrow) * K + k0 + lcol;
    g2l16(Ag,                       &As[nb][0][wid * 1024]);
    g2l16(Ag + (size_t)16 * K,      &As[nb][0][wid * 1024 + 512]);
    g2l16(Ag + 32,                  &As[nb][1][wid * 1024]);
    g2l16(Ag + (size_t)16 * K + 32, &As[nb][1][wid * 1024 + 512]);
    const ushort* Bg = B + (size_t)(n0 + wid * 16 + lrow) * K + k0 + lcol;
    g2l16(Bg,      &Bs[nb][0][wid * 512]);
    g2l16(Bg + 32, &Bs[nb][1][wid * 512]);
  };

  stage(0, 0);
  for (int k0 = 0; k0 < K; k0 += 64) {
    const int nb = (k0 >> 6) & 1;
    __syncthreads();
    if (k0 + 64 < K) stage(k0 + 64, nb ^ 1);

#pragma unroll
    for (int ks = 0; ks < 2; ks++) {
      bf16x8 af[4], bfr[2];
#pragma unroll
      for (int t = 0; t < 4; t++)
        af[t] = *(const bf16x8*)&As[nb][ks][(wm + t * 16 + lc) * 32 + quad * 8];
#pragma unroll
      for (int t = 0; t < 2; t++)
        bfr[t] = *(const bf16x8*)&Bs[nb][ks][(wn + t * 16 + lc) * 32 + quad * 8];
#pragma unroll
      for (int mt = 0; mt < 4; mt++)
#pragma unroll
        for (int nt = 0; nt < 2; nt++)
          acc[mt][nt] = __builtin_amdgcn_mfma_f32_16x16x32_bf16(af[mt], bfr[nt], acc[mt][nt], 0, 0, 0);
    }
  }

#pragma unroll
  for (int mt = 0; mt < 4; mt++) {
#pragma unroll
    for (int r = 0; r < 4; r++) {
      int row = m0 + wm + mt * 16 + quad * 4 + r;
#pragma unroll
      for (int nt = 0; nt < 2; nt++) {
        int col = n0 + wn + nt * 16 + lc;
        C[(size_t)row * 1024 + col] = acc[mt][nt][r] + bias[col];
      }
    }
  }
}

// ---------------- chunked flash attention: 2 waves x 32q, single-barrier dbuf ----------------
// Grid (80, 32): blockIdx.y = bh; blockIdx.x -> (64-query block qi, key-chunk ci of <=8
// key-tiles of 64). Partials combine by addition (no-max softmax) via atomicAdd.
// Staging double-buffered: barrier -> prefetch(kt+1) -> compute(kt); one barrier/tile.
__global__ __launch_bounds__(128, 3) void attn_kernel(const ushort* __restrict__ Qb,
                                                      const ushort* __restrict__ Kb,
                                                      const ushort* __restrict__ Vt,
                                                      float* __restrict__ O32,
                                                      float* __restrict__ L32) {
  __shared__ __align__(16) ushort Ks[2][2][2048];   // [buf][d-half][key 64][d 32]
  __shared__ __align__(16) ushort Vs[2][2][2048];   // [buf][k-half][d 64][k 32]
  __shared__ __align__(16) ushort Ps[2][32][72];    // per-wave P tile [q 32][k 64+pad]

  const int bh = blockIdx.y, b = bh >> 4, h = bh & 15;
  // decode chunk id, heavy (8-tile) chunks first (round-4 proven)
  const int f = 79 - (int)blockIdx.x;
  int qi, ci;
  if (f < 8)       { qi = f;                 ci = 0; }
  else if (f < 24) { int g = f - 8;  qi = 8  + (g >> 1); ci = g & 1; }
  else if (f < 48) { int g = f - 24; int q3 = g / 3; qi = 16 + q3; ci = g - 3 * q3; }
  else             { int g = f - 48; qi = 24 + (g >> 2); ci = g & 3; }
  const int t0 = ci * 8;
  const int t1 = min(t0 + 8, qi + 1);

  const int tid = threadIdx.x, lane = tid & 63, wid = tid >> 6;   // wid in {0,1}
  const int quad = lane >> 4, lc = lane & 15;
  const int lrow = lane >> 2, lcol = (lane & 3) * 8;
  const int qbw = qi * 64 + wid * 32;

  const size_t kbase = (size_t)(b * 2048) * 1024 + h * 64;
  const size_t vbase = (size_t)bh * 131072;

  // Q fragments (A-layout), resident: 2 q-tiles x 2 k-halves
  bf16x8 qf[2][2];
#pragma unroll
  for (int t = 0; t < 2; t++) {
    const ushort* Qp = Qb + kbase + (size_t)(qbw + t * 16 + lc) * 1024;
    qf[t][0] = *(const bf16x8*)(Qp + quad * 8);
    qf[t][1] = *(const bf16x8*)(Qp + 32 + quad * 8);
  }

  bf16x8 ones;
#pragma unroll
  for (int j = 0; j < 8; j++) ones[j] = (short)0x3f80;   // bf16 1.0

  f32x4 o_acc[2][4] = {};
  f32x4 l_acc[2] = {};

  auto stage = [&](int kb, int nb) {
    // wave wid stages d-half (K) / k-half (V) = wid, row-groups 0..3
#pragma unroll
    for (int j = 0; j < 4; j++) {
      const ushort* gK = Kb + kbase + (size_t)(kb + j * 16 + lrow) * 1024 + wid * 32 + lcol;
      g2l16(gK, &Ks[nb][wid][j * 512]);
      const ushort* gV = Vt + vbase + (size_t)(j * 16 + lrow) * 2048 + kb + wid * 32 + lcol;
      g2l16(gV, &Vs[nb][wid][j * 512]);
    }
  };

  stage(t0 * 64, 0);
  for (int kt = t0; kt < t1; kt++) {
    const int kb = kt * 64;
    const int nb = (kt - t0) & 1;
    __syncthreads();                              // drains prefetch issued last iteration
    if (kt + 1 < t1) stage(kb + 64, nb ^ 1);      // prefetch overlaps compute below

    // K fragments hoisted, shared across both q-tiles
    bf16x8 kf[4][2];
#pragma unroll
    for (int c = 0; c < 4; c++) {
      kf[c][0] = *(const bf16x8*)&Ks[nb][0][(c * 16 + lc) * 32 + quad * 8];
      kf[c][1] = *(const bf16x8*)&Ks[nb][1][(c * 16 + lc) * 32 + quad * 8];
    }

    // S = Q K^T (2 q-tiles x 64 keys), mask, exp2, scatter P
#pragma unroll
    for (int c = 0; c < 4; c++) {
#pragma unroll
      for (int t = 0; t < 2; t++) {
        f32x4 z = {};
        z = __builtin_amdgcn_mfma_f32_16x16x32_bf16(qf[t][0], kf[c][0], z, 0, 0, 0);
        z = __builtin_amdgcn_mfma_f32_16x16x32_bf16(qf[t][1], kf[c][1], z, 0, 0, 0);
        const bool diag = (kb + 63 > qbw + t * 16);   // wave-uniform
#pragma unroll
        for (int r = 0; r < 4; r++) {
          float sv = z[r];
          if (diag && (kb + c * 16 + lc > qbw + t * 16 + quad * 4 + r)) sv = -1e30f;
          Ps[wid][t * 16 + quad * 4 + r][c * 16 + lc] = f2bf(__builtin_amdgcn_exp2f(sv));
        }
      }
    }
    __asm__ volatile("s_waitcnt lgkmcnt(0)" ::: "memory");  // wave-local P ordering
    bf16x8 ap[2][2];
#pragma unroll
    for (int t = 0; t < 2; t++) {
      ap[t][0] = *(const bf16x8*)&Ps[wid][t * 16 + lc][quad * 8];
      ap[t][1] = *(const bf16x8*)&Ps[wid][t * 16 + lc][32 + quad * 8];
    }

    // l += P @ ones  (row sums via matrix pipe)
#pragma unroll
    for (int t = 0; t < 2; t++) {
      l_acc[t] = __builtin_amdgcn_mfma_f32_16x16x32_bf16(ap[t][0], ones, l_acc[t], 0, 0, 0);
      l_acc[t] = __builtin_amdgcn_mfma_f32_16x16x32_bf16(ap[t][1], ones, l_acc[t], 0, 0, 0);
    }

    // O += P V (V fragments shared across both q-tiles)
#pragma unroll
    for (int nt = 0; nt < 4; nt++) {
      bf16x8 vb0 = *(const bf16x8*)&Vs[nb][0][(nt * 16 + lc) * 32 + quad * 8];
      bf16x8 vb1 = *(const bf16x8*)&Vs[nb][1][(nt * 16 + lc) * 32 + quad * 8];
#pragma unroll
      for (int t = 0; t < 2; t++) {
        o_acc[t][nt] = __builtin_amdgcn_mfma_f32_16x16x32_bf16(ap[t][0], vb0, o_acc[t][nt], 0, 0, 0);
        o_acc[t][nt] = __builtin_amdgcn_mfma_f32_16x16x32_bf16(ap[t][1], vb1, o_acc[t][nt], 0, 0, 0);
      }
    }
  }

  // partial (O, l) -> global accumulators
#pragma unroll
  for (int t = 0; t < 2; t++) {
    if (lc == 0) {
#pragma unroll
      for (int r = 0; r < 4; r++)
        atomicAdd(&L32[(size_t)bh * 2048 + qbw + t * 16 + quad * 4 + r], l_acc[t][r]);
    }
#pragma unroll
    for (int r = 0; r < 4; r++) {
      size_t orow = ((size_t)(b * 2048) + qbw + t * 16 + quad * 4 + r) * 1024 + h * 64 + lc;
#pragma unroll
      for (int nt = 0; nt < 4; nt++)
        atomicAdd(&O32[orow + nt * 16], o_acc[t][nt][r]);
    }
  }
}

// ---------------- normalize: O32/l -> bf16 attn_out ----------------
__global__ __launch_bounds__(256) void normalize_kernel(const float* __restrict__ O32,
                                                        const float* __restrict__ L32,
                                                        ushort* __restrict__ Out) {
  const int row = blockIdx.x;            // 0..4095  (b*2048 + t)
  const int tid = threadIdx.x;
  const int col = tid * 4;
  const int b = row >> 11, t = row & 2047, h = col >> 6;
  const float inv = 1.0f / L32[(size_t)(b * 16 + h) * 2048 + t];
  float4 o = ((const float4*)(O32 + (size_t)row * 1024))[tid];
  ushort4 u;
  u.x = f2bf(o.x * inv); u.y = f2bf(o.y * inv);
  u.z = f2bf(o.z * inv); u.w = f2bf(o.w * inv);
  ((ushort4*)(Out + (size_t)row * 1024))[tid] = u;
}

// ---------------- launcher ----------------
extern "C" void kernel_launch(void* const* d_in, const int* in_sizes, int n_in,
                              void* d_out, int out_size, void* d_ws, size_t ws_size,
                              hipStream_t stream) {
  const float* x  = (const float*)d_in[0];
  const float* Wq = (const float*)d_in[1];
  const float* Wk = (const float*)d_in[2];
  const float* Wv = (const float*)d_in[3];
  const float* Wo = (const float*)d_in[4];
  const float* bo = (const float*)d_in[5];
  float* out = (float*)d_out;

  char* ws = (char*)d_ws;
  ushort* xbf  = (ushort*)(ws);                  //  8 MB: x bf16 (dead after gemm_qkv)
  ushort* wcat = (ushort*)(ws + (8ull  << 20));  //  8 MB: Wcat bf16
  ushort* qkv  = (ushort*)(ws + (16ull << 20));  // 24 MB: Q | K | Vt planes
  ushort* Qp   = qkv;
  ushort* Kp   = qkv + (1ull << 22);
  ushort* Vt   = qkv + (2ull << 22);             // V written directly transposed
  float*  L32  = (float*)ws;                     // 256 KB over dead xbf
  float*  O32  = out;                            // d_out as fp32 accumulator scratch
  ushort* attn_out = Qp;                         // Q plane free after attn

  // cast x+weights, zero O32 (12288 blocks = 3M threads)
  cast_all<<<12288, 256, 0, stream>>>(x, Wq, Wk, Wv, Wo, xbf, wcat, (float4*)O32);

  // QKV = x @ Wcat[0:3072]^T; Q pre-scaled by 0.125*log2e; V transposed in epilogue via LDS
  gemm_qkv<<<dim3(24, 32), 256, 0, stream>>>(xbf, wcat, qkv, Vt);

  hipMemsetAsync(L32, 0, (size_t)32 * 2048 * 4, stream);

  attn_kernel<<<dim3(80, 32), 128, 0, stream>>>(Qp, Kp, Vt, O32, L32);

  normalize_kernel<<<4096, 256, 0, stream>>>(O32, L32, attn_out);

  // out = attn_out @ Wo^T + bo   (overwrites O32 scratch, stream-ordered)
  gemm_proj<<<dim3(16, 32), 256, 0, stream>>>(
      attn_out, wcat + (size_t)3072 * 1024, out, bo);
}

// Round 10
// 203.728 us; speedup vs baseline: 1.0631x; 1.0631x over previous
//
#include <hip/hip_runtime.h>
#include <math.h>

typedef __attribute__((ext_vector_type(8))) short bf16x8;
typedef __attribute__((ext_vector_type(4))) float f32x4;

__device__ __forceinline__ ushort f2bf(float f) {
  union { float f; unsigned u; } v; v.f = f;
  return (ushort)((v.u + 0x8000u) >> 16);
}

// async global->LDS, 16B per lane. lds base wave-uniform; lane i lands at base + i*16B.
__device__ __forceinline__ void g2l16(const void* g, void* l) {
  __builtin_amdgcn_global_load_lds((const __attribute__((address_space(1))) unsigned*)g,
                                   (__attribute__((address_space(3))) unsigned*)l, 16, 0, 0);
}

// ---------------- merged cast + zero kernel ----------------
// idx [0,1M): x -> xbf.  [1M,2M): weights -> wcat (Wq scaled).  [2M,3M): zero O32.
__global__ __launch_bounds__(256) void cast_all(const float* __restrict__ x,
                                                const float* __restrict__ Wq,
                                                const float* __restrict__ Wk,
                                                const float* __restrict__ Wv,
                                                const float* __restrict__ Wo,
                                                ushort* __restrict__ xbf,
                                                ushort* __restrict__ wcat,
                                                float4* __restrict__ O32) {
  int i = blockIdx.x * 256 + threadIdx.x;
  if (i < 1048576) {
    float4 v = ((const float4*)x)[i];
    ushort4 u; u.x = f2bf(v.x); u.y = f2bf(v.y); u.z = f2bf(v.z); u.w = f2bf(v.w);
    ((ushort4*)xbf)[i] = u;
  } else if (i < 2097152) {
    int j = i - 1048576;
    int sel = j >> 18;
    const float* src = (sel == 0) ? Wq : (sel == 1) ? Wk : (sel == 2) ? Wv : Wo;
    float scale = (sel == 0) ? 0.125f * 1.44269504088896f : 1.0f;  // fold D^-0.5 * log2e
    float4 v = ((const float4*)src)[j & 0x3FFFF];
    ushort4 u;
    u.x = f2bf(v.x * scale); u.y = f2bf(v.y * scale);
    u.z = f2bf(v.z * scale); u.w = f2bf(v.w * scale);
    ((ushort4*)wcat)[j] = u;
  } else {
    O32[i - 2097152] = float4{0.f, 0.f, 0.f, 0.f};
  }
}

// ---------------- QKV GEMM: C = A @ B^T, 128x128, BK=32, dbuf ----------------
// Q/K planes token-major; V blocks write Vt[bh][d][t] via LDS transpose in the epilogue.
__global__ __launch_bounds__(256) void gemm_qkv(const ushort* __restrict__ A,
                                                const ushort* __restrict__ B,
                                                ushort* __restrict__ C3,
                                                ushort* __restrict__ Vt) {
  const int K = 1024;
  __shared__ __align__(16) ushort smem[17408];   // staging 32KB / transpose T[128][136]
  ushort* As = smem;           // [2][128*32]
  ushort* Bs = smem + 8192;    // [2][128*32]
  const int m0 = blockIdx.y * 128, n0 = blockIdx.x * 128;
  const int tid = threadIdx.x, lane = tid & 63, wid = tid >> 6;
  const int quad = lane >> 4, lc = lane & 15;
  const int lrow = lane >> 2, lcol = (lane & 3) * 8;
  const int wm = (wid >> 1) * 64, wn = (wid & 1) * 64;

  f32x4 acc[4][4] = {};

  auto stage = [&](int k0, int nb) {
    const ushort* Ag = A + (size_t)(m0 + wid * 32 + lrow) * K + k0 + lcol;
    g2l16(Ag, &As[nb * 4096 + wid * 1024]);
    g2l16(Ag + (size_t)16 * K, &As[nb * 4096 + wid * 1024 + 512]);
    const ushort* Bg = B + (size_t)(n0 + wid * 32 + lrow) * K + k0 + lcol;
    g2l16(Bg, &Bs[nb * 4096 + wid * 1024]);
    g2l16(Bg + (size_t)16 * K, &Bs[nb * 4096 + wid * 1024 + 512]);
  };

  stage(0, 0);
  for (int k0 = 0; k0 < K; k0 += 32) {
    const int nb = (k0 >> 5) & 1;
    __syncthreads();
    if (k0 + 32 < K) stage(k0 + 32, nb ^ 1);

    bf16x8 af[4], bfr[4];
#pragma unroll
    for (int t = 0; t < 4; t++)
      af[t] = *(const bf16x8*)&As[nb * 4096 + (wm + t * 16 + lc) * 32 + quad * 8];
#pragma unroll
    for (int t = 0; t < 4; t++)
      bfr[t] = *(const bf16x8*)&Bs[nb * 4096 + (wn + t * 16 + lc) * 32 + quad * 8];
#pragma unroll
    for (int mt = 0; mt < 4; mt++)
#pragma unroll
      for (int nt = 0; nt < 4; nt++)
        acc[mt][nt] = __builtin_amdgcn_mfma_f32_16x16x32_bf16(af[mt], bfr[nt], acc[mt][nt], 0, 0, 0);
  }

  const int sel = n0 >> 10;   // 0=Q, 1=K, 2=V (block-uniform)
  if (sel < 2) {
#pragma unroll
    for (int mt = 0; mt < 4; mt++) {
#pragma unroll
      for (int r = 0; r < 4; r++) {
        int row = m0 + wm + mt * 16 + quad * 4 + r;
#pragma unroll
        for (int nt = 0; nt < 4; nt++) {
          int col = n0 + wn + nt * 16 + lc;
          size_t dst = ((size_t)sel << 22) + (size_t)row * 1024 + (col & 1023);
          C3[dst] = f2bf(acc[mt][nt][r]);
        }
      }
    }
  } else {
    // transpose through LDS: T[d_local 128][token_local 128], pitch 136
    __syncthreads();
#pragma unroll
    for (int mt = 0; mt < 4; mt++)
#pragma unroll
      for (int r = 0; r < 4; r++) {
        int tl = wm + mt * 16 + quad * 4 + r;
#pragma unroll
        for (int nt = 0; nt < 4; nt++)
          smem[(wn + nt * 16 + lc) * 136 + tl] = f2bf(acc[mt][nt][r]);
      }
    __syncthreads();
    const int hd0 = n0 - 2048, b = m0 >> 11, t_base = m0 & 2047;
#pragma unroll
    for (int i = 0; i < 8; i++) {
      int idx = i * 256 + tid;
      int dl = idx >> 4, tc = (idx & 15) * 8;
      uint4 v = *(const uint4*)&smem[dl * 136 + tc];
      int hd = hd0 + dl;
      *(uint4*)(Vt + (size_t)(b * 16 + (hd >> 6)) * 131072 +
                (size_t)(hd & 63) * 2048 + t_base + tc) = v;
    }
  }
}

// ---------------- proj GEMM: out[4096][1024] = attn_out @ Wo^T + bo, BK=64 ----------------
__global__ __launch_bounds__(256) void gemm_proj(const ushort* __restrict__ A,
                                                 const ushort* __restrict__ B,
                                                 float* __restrict__ C,
                                                 const float* __restrict__ bias) {
  const int K = 1024;
  __shared__ __align__(16) ushort As[2][2][128 * 32];
  __shared__ __align__(16) ushort Bs[2][2][64 * 32];
  const int m0 = blockIdx.y * 128, n0 = blockIdx.x * 64;
  const int tid = threadIdx.x, lane = tid & 63, wid = tid >> 6;
  const int quad = lane >> 4, lc = lane & 15;
  const int lrow = lane >> 2, lcol = (lane & 3) * 8;
  const int wm = (wid >> 1) * 64, wn = (wid & 1) * 32;

  f32x4 acc[4][2] = {};

  auto stage = [&](int k0, int nb) {
    const ushort* Ag = A + (size_t)(m0 + wid * 32 + lrow) * K + k0 + lcol;
    g2l16(Ag,                       &As[nb][0][wid * 1024]);
    g2l16(Ag + (size_t)16 * K,      &As[nb][0][wid * 1024 + 512]);
    g2l16(Ag + 32,                  &As[nb][1][wid * 1024]);
    g2l16(Ag + (size_t)16 * K + 32, &As[nb][1][wid * 1024 + 512]);
    const ushort* Bg = B + (size_t)(n0 + wid * 16 + lrow) * K + k0 + lcol;
    g2l16(Bg,      &Bs[nb][0][wid * 512]);
    g2l16(Bg + 32, &Bs[nb][1][wid * 512]);
  };

  stage(0, 0);
  for (int k0 = 0; k0 < K; k0 += 64) {
    const int nb = (k0 >> 6) & 1;
    __syncthreads();
    if (k0 + 64 < K) stage(k0 + 64, nb ^ 1);

#pragma unroll
    for (int ks = 0; ks < 2; ks++) {
      bf16x8 af[4], bfr[2];
#pragma unroll
      for (int t = 0; t < 4; t++)
        af[t] = *(const bf16x8*)&As[nb][ks][(wm + t * 16 + lc) * 32 + quad * 8];
#pragma unroll
      for (int t = 0; t < 2; t++)
        bfr[t] = *(const bf16x8*)&Bs[nb][ks][(wn + t * 16 + lc) * 32 + quad * 8];
#pragma unroll
      for (int mt = 0; mt < 4; mt++)
#pragma unroll
        for (int nt = 0; nt < 2; nt++)
          acc[mt][nt] = __builtin_amdgcn_mfma_f32_16x16x32_bf16(af[mt], bfr[nt], acc[mt][nt], 0, 0, 0);
    }
  }

#pragma unroll
  for (int mt = 0; mt < 4; mt++) {
#pragma unroll
    for (int r = 0; r < 4; r++) {
      int row = m0 + wm + mt * 16 + quad * 4 + r;
#pragma unroll
      for (int nt = 0; nt < 2; nt++) {
        int col = n0 + wn + nt * 16 + lc;
        C[(size_t)row * 1024 + col] = acc[mt][nt][r] + bias[col];
      }
    }
  }
}

// ---------------- chunked flash attention: 4 waves x 32q = 128q/block, dbuf ----------------
// Grid (40, 32): blockIdx.y = bh; blockIdx.x -> (128-q block qi, key-chunk ci of <=8
// key-tiles of 64). Partials combine by addition (no-max softmax) via atomicAdd.
// Single barrier per tile: sync -> prefetch(kt+1, buf^1) -> compute(kt, buf).
// l computed by MFMA with B=ones.
__global__ __launch_bounds__(256, 3) void attn_kernel(const ushort* __restrict__ Qb,
                                                      const ushort* __restrict__ Kb,
                                                      const ushort* __restrict__ Vt,
                                                      float* __restrict__ O32,
                                                      float* __restrict__ L32) {
  __shared__ __align__(16) ushort Ks[2][2][2048];   // [buf][d-half][key 64][d 32]
  __shared__ __align__(16) ushort Vs[2][2][2048];   // [buf][k-half][d 64][k 32]
  __shared__ __align__(16) ushort Ps[4][32][72];    // per-wave P tile [q 32][k 64+pad]

  const int bh = blockIdx.y, b = bh >> 4, h = bh & 15;
  // decode (qi, ci): low blockIdx.x = heaviest q-blocks first (round-7 proven)
  const int f = (int)blockIdx.x;
  int qi, ci;
  if (f < 16)      { qi = 12 + (f >> 2); ci = f & 3; }
  else if (f < 28) { int g = f - 16; int q3 = g / 3; qi = 8 + q3; ci = g - 3 * q3; }
  else if (f < 36) { int g = f - 28; qi = 4 + (g >> 1); ci = g & 1; }
  else             { qi = f - 36; ci = 0; }
  const int t0 = ci * 8;
  const int t1 = min(t0 + 8, 2 * qi + 2);

  const int tid = threadIdx.x, lane = tid & 63, wid = tid >> 6;
  const int quad = lane >> 4, lc = lane & 15;
  const int lrow = lane >> 2, lcol = (lane & 3) * 8;
  const int qbw = qi * 128 + wid * 32;

  const size_t kbase = (size_t)(b * 2048) * 1024 + h * 64;
  const size_t vbase = (size_t)bh * 131072;

  // Q fragments (A-layout), resident: 2 q-tiles x 2 k-halves
  bf16x8 qf[2][2];
#pragma unroll
  for (int t = 0; t < 2; t++) {
    const ushort* Qp = Qb + kbase + (size_t)(qbw + t * 16 + lc) * 1024;
    qf[t][0] = *(const bf16x8*)(Qp + quad * 8);
    qf[t][1] = *(const bf16x8*)(Qp + 32 + quad * 8);
  }

  bf16x8 ones;
#pragma unroll
  for (int j = 0; j < 8; j++) ones[j] = (short)0x3f80;   // bf16 1.0

  f32x4 o_acc[2][4] = {};
  f32x4 l_acc[2] = {};

  auto stage = [&](int kb, int nb) {
    // 8 chunks each for K and V across 4 waves (2+2 per wave)
#pragma unroll
    for (int cc = 0; cc < 2; cc++) {
      int ck = wid + cc * 4;
      int half = ck >> 2, rg = ck & 3;
      const ushort* gK = Kb + kbase + (size_t)(kb + rg * 16 + lrow) * 1024 + half * 32 + lcol;
      g2l16(gK, &Ks[nb][half][rg * 512]);
      const ushort* gV = Vt + vbase + (size_t)(rg * 16 + lrow) * 2048 + kb + half * 32 + lcol;
      g2l16(gV, &Vs[nb][half][rg * 512]);
    }
  };

  stage(t0 * 64, 0);
  for (int kt = t0; kt < t1; kt++) {
    const int kb = kt * 64;
    const int nb = (kt - t0) & 1;
    __syncthreads();                              // drains prefetch issued last iter (landed)
    if (kt + 1 < t1) stage(kb + 64, nb ^ 1);      // prefetch overlaps compute below

    // K fragments hoisted, shared across both q-tiles
    bf16x8 kf[4][2];
#pragma unroll
    for (int c = 0; c < 4; c++) {
      kf[c][0] = *(const bf16x8*)&Ks[nb][0][(c * 16 + lc) * 32 + quad * 8];
      kf[c][1] = *(const bf16x8*)&Ks[nb][1][(c * 16 + lc) * 32 + quad * 8];
    }

    // S = Q K^T (2 q-tiles x 64 keys), mask, exp2, scatter P
#pragma unroll
    for (int c = 0; c < 4; c++) {
#pragma unroll
      for (int t = 0; t < 2; t++) {
        f32x4 z = {};
        z = __builtin_amdgcn_mfma_f32_16x16x32_bf16(qf[t][0], kf[c][0], z, 0, 0, 0);
        z = __builtin_amdgcn_mfma_f32_16x16x32_bf16(qf[t][1], kf[c][1], z, 0, 0, 0);
        const bool diag = (kb + 63 > qbw + t * 16);   // wave-uniform
#pragma unroll
        for (int r = 0; r < 4; r++) {
          float sv = z[r];
          if (diag && (kb + c * 16 + lc > qbw + t * 16 + quad * 4 + r)) sv = -1e30f;
          Ps[wid][t * 16 + quad * 4 + r][c * 16 + lc] = f2bf(__builtin_amdgcn_exp2f(sv));
        }
      }
    }
    __asm__ volatile("s_waitcnt lgkmcnt(0)" ::: "memory");  // wave-local P ordering
    bf16x8 ap[2][2];
#pragma unroll
    for (int t = 0; t < 2; t++) {
      ap[t][0] = *(const bf16x8*)&Ps[wid][t * 16 + lc][quad * 8];
      ap[t][1] = *(const bf16x8*)&Ps[wid][t * 16 + lc][32 + quad * 8];
    }

    // l += P @ ones  (row sums via matrix pipe)
#pragma unroll
    for (int t = 0; t < 2; t++) {
      l_acc[t] = __builtin_amdgcn_mfma_f32_16x16x32_bf16(ap[t][0], ones, l_acc[t], 0, 0, 0);
      l_acc[t] = __builtin_amdgcn_mfma_f32_16x16x32_bf16(ap[t][1], ones, l_acc[t], 0, 0, 0);
    }

    // O += P V (V fragments shared across both q-tiles)
#pragma unroll
    for (int nt = 0; nt < 4; nt++) {
      bf16x8 vb0 = *(const bf16x8*)&Vs[nb][0][(nt * 16 + lc) * 32 + quad * 8];
      bf16x8 vb1 = *(const bf16x8*)&Vs[nb][1][(nt * 16 + lc) * 32 + quad * 8];
#pragma unroll
      for (int t = 0; t < 2; t++) {
        o_acc[t][nt] = __builtin_amdgcn_mfma_f32_16x16x32_bf16(ap[t][0], vb0, o_acc[t][nt], 0, 0, 0);
        o_acc[t][nt] = __builtin_amdgcn_mfma_f32_16x16x32_bf16(ap[t][1], vb1, o_acc[t][nt], 0, 0, 0);
      }
    }
  }

  // partial (O, l) -> global accumulators
#pragma unroll
  for (int t = 0; t < 2; t++) {
    if (lc == 0) {
#pragma unroll
      for (int r = 0; r < 4; r++)
        atomicAdd(&L32[(size_t)bh * 2048 + qbw + t * 16 + quad * 4 + r], l_acc[t][r]);
    }
#pragma unroll
    for (int r = 0; r < 4; r++) {
      size_t orow = ((size_t)(b * 2048) + qbw + t * 16 + quad * 4 + r) * 1024 + h * 64 + lc;
#pragma unroll
      for (int nt = 0; nt < 4; nt++)
        atomicAdd(&O32[orow + nt * 16], o_acc[t][nt][r]);
    }
  }
}

// ---------------- normalize: O32/l -> bf16 attn_out ----------------
__global__ __launch_bounds__(256) void normalize_kernel(const float* __restrict__ O32,
                                                        const float* __restrict__ L32,
                                                        ushort* __restrict__ Out) {
  const int row = blockIdx.x;            // 0..4095  (b*2048 + t)
  const int tid = threadIdx.x;
  const int col = tid * 4;
  const int b = row >> 11, t = row & 2047, h = col >> 6;
  const float inv = 1.0f / L32[(size_t)(b * 16 + h) * 2048 + t];
  float4 o = ((const float4*)(O32 + (size_t)row * 1024))[tid];
  ushort4 u;
  u.x = f2bf(o.x * inv); u.y = f2bf(o.y * inv);
  u.z = f2bf(o.z * inv); u.w = f2bf(o.w * inv);
  ((ushort4*)(Out + (size_t)row * 1024))[tid] = u;
}

// ---------------- launcher ----------------
extern "C" void kernel_launch(void* const* d_in, const int* in_sizes, int n_in,
                              void* d_out, int out_size, void* d_ws, size_t ws_size,
                              hipStream_t stream) {
  const float* x  = (const float*)d_in[0];
  const float* Wq = (const float*)d_in[1];
  const float* Wk = (const float*)d_in[2];
  const float* Wv = (const float*)d_in[3];
  const float* Wo = (const float*)d_in[4];
  const float* bo = (const float*)d_in[5];
  float* out = (float*)d_out;

  char* ws = (char*)d_ws;
  ushort* xbf  = (ushort*)(ws);                  //  8 MB: x bf16 (dead after gemm_qkv)
  ushort* wcat = (ushort*)(ws + (8ull  << 20));  //  8 MB: Wcat bf16
  ushort* qkv  = (ushort*)(ws + (16ull << 20));  // 24 MB: Q | K | Vt planes
  ushort* Qp   = qkv;
  ushort* Kp   = qkv + (1ull << 22);
  ushort* Vt   = qkv + (2ull << 22);             // V written directly transposed
  float*  L32  = (float*)ws;                     // 256 KB over dead xbf
  float*  O32  = out;                            // d_out as fp32 accumulator scratch
  ushort* attn_out = Qp;                         // Q plane free after attn

  // cast x+weights, zero O32 (12288 blocks = 3M threads)
  cast_all<<<12288, 256, 0, stream>>>(x, Wq, Wk, Wv, Wo, xbf, wcat, (float4*)O32);

  // QKV = x @ Wcat[0:3072]^T; Q pre-scaled by 0.125*log2e; V transposed in epilogue via LDS
  gemm_qkv<<<dim3(24, 32), 256, 0, stream>>>(xbf, wcat, qkv, Vt);

  hipMemsetAsync(L32, 0, (size_t)32 * 2048 * 4, stream);

  attn_kernel<<<dim3(40, 32), 256, 0, stream>>>(Qp, Kp, Vt, O32, L32);

  normalize_kernel<<<4096, 256, 0, stream>>>(O32, L32, attn_out);

  // out = attn_out @ Wo^T + bo   (overwrites O32 scratch, stream-ordered)
  gemm_proj<<<dim3(16, 32), 256, 0, stream>>>(
      attn_out, wcat + (size_t)3072 * 1024, out, bo);
}